// Round 2
// baseline (598.772 us; speedup 1.0000x reference)
//
#include <hip/hip_runtime.h>
#include <hip/hip_bf16.h>

// GCN 2-layer forward. CSR pull-aggregation, wave-per-node gathers.
// GEMMs are BARRIER-FREE and LDS-FREE: per-wave row ownership, A register-
// prefetch distance 2, B fragments read directly from L2-resident packed
// weights. This round: (1) fill_csr + gemm1 MERGED into one dispatch
// (independent work, gemm1 blocks first, fill backfills CUs -> concurrent);
// (2) agg1/agg2 restructured to one WAVE per node (4x16 / 8x8 lane split,
// shfl_xor reduce) killing max-of-4 degree divergence; (3) h2 rows padded
// 40->48 (exactly 2 cache lines, aligned); (4) f2bf via v_cvt_pk_bf16_f32.
// N=100000, F_IN=512, HID=128, C=40, E=1.6M

#define F_IN 512
#define HID  128
#define NC   40
#define NCP  48   // padded h2 row: 96 B = exactly two 64 B lines, 16 B aligned

typedef __attribute__((ext_vector_type(8))) short bf16x8;
typedef __attribute__((ext_vector_type(4))) float f32x4v;

__device__ __forceinline__ ushort f2bf(float f) {
    unsigned r;
    asm("v_cvt_pk_bf16_f32 %0, %1, %1" : "=v"(r) : "v"(f));   // RNE, 1 instr
    return (ushort)r;
}
__device__ __forceinline__ unsigned cvtpk(float a, float b) {
    unsigned r;
    asm("v_cvt_pk_bf16_f32 %0, %1, %2" : "=v"(r) : "v"(a), "v"(b));
    return r;
}
__device__ __forceinline__ float bf2f(ushort u) {
    return __uint_as_float((unsigned)u << 16);
}
__device__ __forceinline__ bf16x8 cvt8(float4 lo, float4 hi) {
    union { unsigned u[4]; bf16x8 v; } t;
    t.u[0] = cvtpk(lo.x, lo.y); t.u[1] = cvtpk(lo.z, lo.w);
    t.u[2] = cvtpk(hi.x, hi.y); t.u[3] = cvtpk(hi.z, hi.w);
    return t.v;
}

// ---------------- degree count (real edges) + weight pack, one launch -------
// Blocks [0, EB): per-edge atomic degree count.
// Blocks [EB, EB+280): pack W1 -> W1p bf16 and W2 -> W2p bf16 (padded).
// W1p: [s(16)][kb(4)][n(128)][j(8)], k = s*32+kb*8+j   (65536 elems)
// W2p: [ks(4)][kb(4)][n(48)][j(8)],  k = ks*32+kb*8+j  (6144 elems, n>=40 -> 0)
__global__ void prep_k(const int* __restrict__ dst, int E, int EB,
                       unsigned* __restrict__ cnt,
                       const float* __restrict__ W1, const float* __restrict__ W2,
                       ushort* __restrict__ W1p, ushort* __restrict__ W2p) {
    int b = blockIdx.x;
    if (b < EB) {
        int t = b * 256 + threadIdx.x;
        if (t < E) atomicAdd(&cnt[dst[t]], 1u);
        return;
    }
    int t = (b - EB) * 256 + threadIdx.x;
    if (t < 65536) {
        int j = t & 7, n = (t >> 3) & 127, kb = (t >> 10) & 3, s = t >> 12;
        int k = s * 32 + kb * 8 + j;
        W1p[t] = f2bf(W1[(size_t)k * HID + n]);
    } else {
        int q = t - 65536;
        if (q < 6144) {
            int j = q & 7;
            int i2 = q >> 3;
            int n = i2 % 48;
            int i3 = i2 / 48;
            int kb = i3 & 3, ks = i3 >> 2;
            int k = ks * 32 + kb * 8 + j;
            float v = (n < NC) ? W2[(size_t)k * NC + n] : 0.f;
            W2p[q] = f2bf(v);
        }
    }
}

// ---------------- block-local exclusive scan (shfl-based) + fused dis -------
__global__ __launch_bounds__(1024) void scan_block(const unsigned* __restrict__ cnt,
                                                   unsigned* __restrict__ offs,
                                                   unsigned* __restrict__ bsums,
                                                   float* __restrict__ dis, int N) {
    int tid = threadIdx.x;
    int i = blockIdx.x * 1024 + tid;
    unsigned v = (i < N) ? cnt[i] : 0u;
    if (i < N) dis[i] = rsqrtf((float)v + 1.0f);   // +1 = self loop
    int lane = tid & 63, w = tid >> 6;
    unsigned s = v;
    #pragma unroll
    for (int d = 1; d < 64; d <<= 1) {
        unsigned t = __shfl_up(s, d, 64);
        if (lane >= d) s += t;
    }
    __shared__ unsigned wt[16];
    if (lane == 63) wt[w] = s;
    __syncthreads();
    unsigned add = 0;
    #pragma unroll
    for (int j = 0; j < 16; j++) add += (j < w) ? wt[j] : 0u;
    unsigned incl = s + add;
    if (i < N) offs[i] = incl - v;                 // exclusive within block
    if (tid == 1023) bsums[blockIdx.x] = incl;     // raw block total
}

// ---------------- add bsums prefix (computed in-block, no serial kernel) ----
__global__ __launch_bounds__(1024) void scan_add2(unsigned* __restrict__ offs,
                                                  const unsigned* __restrict__ bsums,
                                                  int N, unsigned total) {
    int i = blockIdx.x * 1024 + threadIdx.x;
    int lane = threadIdx.x & 63;
    unsigned s = 0;
    for (int j = lane; j < (int)blockIdx.x; j += 64) s += bsums[j];
    #pragma unroll
    for (int d = 1; d < 64; d <<= 1) s += __shfl_xor(s, d, 64);
    if (i < N) offs[i] += s;
    if (i == 0) offs[N] = total;
}

// ------- MERGED: gemm1 (blocks [0,GB)) + fill_csr (blocks [GB,GB+FB)) -------
// Independent work in one dispatch: HBM/MFMA-bound gemm1 runs concurrently
// with atomic-latency-bound fill_csr on other CUs.
// gemm1: h1s[N,128] = (bf16(x) @ W1) * dis[row], barrier-free, LDS-free.
__global__ __launch_bounds__(256) void fill_gemm1(
        const int* __restrict__ src, const int* __restrict__ dst,
        const unsigned* __restrict__ offs, unsigned* __restrict__ cursor,
        int* __restrict__ col, int E, int GB,
        const float* __restrict__ A, const ushort* __restrict__ Bp,
        const float* __restrict__ dis, ushort* __restrict__ C, int N) {
    if (blockIdx.x >= GB) {
        // ---- fill_csr part ----
        int t = (blockIdx.x - GB) * 256 + threadIdx.x;
        if (t < E) {
            int s = src[t], d = dst[t];
            unsigned pos = offs[d] + atomicAdd(&cursor[d], 1u);
            col[pos] = s;
        }
        return;
    }
    // ---- gemm1 part ----
    const int tid  = threadIdx.x;
    const int wave = tid >> 6;
    const int lane = tid & 63;
    const int quad = lane >> 4;
    const int mr   = lane & 15;
    const int base = (blockIdx.x * 4 + wave) * 32;
    if (base >= N) return;
    const int r0 = base + mr;
    const int r1 = base + 16 + mr;
    const bool ok0 = r0 < N, ok1 = r1 < N;
    const float* ap0 = A + (size_t)(ok0 ? r0 : 0) * F_IN + quad * 8;
    const float* ap1 = A + (size_t)(ok1 ? r1 : 0) * F_IN + quad * 8;
    const ushort* bp = Bp + quad * 1024 + mr * 8;   // + s*4096 + t*128

    f32x4v acc0[8], acc1[8];
    #pragma unroll
    for (int t = 0; t < 8; t++) {
        acc0[t] = (f32x4v){0.f, 0.f, 0.f, 0.f};
        acc1[t] = (f32x4v){0.f, 0.f, 0.f, 0.f};
    }

    // A prefetch regs: [buf][r0lo, r0hi, r1lo, r1hi]
    float4 av[2][4];
    #pragma unroll
    for (int b = 0; b < 2; b++) {
        av[b][0] = *(const float4*)(ap0 + b * 32);
        av[b][1] = *(const float4*)(ap0 + b * 32 + 4);
        av[b][2] = *(const float4*)(ap1 + b * 32);
        av[b][3] = *(const float4*)(ap1 + b * 32 + 4);
    }

    for (int s = 0; s < 16; s++) {
        bf16x8 fa0 = cvt8(av[s & 1][0], av[s & 1][1]);
        bf16x8 fa1 = cvt8(av[s & 1][2], av[s & 1][3]);
        if (s < 14) {   // reload this buffer with step s+2 (distance 2)
            av[s & 1][0] = *(const float4*)(ap0 + (s + 2) * 32);
            av[s & 1][1] = *(const float4*)(ap0 + (s + 2) * 32 + 4);
            av[s & 1][2] = *(const float4*)(ap1 + (s + 2) * 32);
            av[s & 1][3] = *(const float4*)(ap1 + (s + 2) * 32 + 4);
        }
        const ushort* bs = bp + s * 4096;
        #pragma unroll
        for (int t = 0; t < 8; t++) {
            bf16x8 b = *(const bf16x8*)(bs + t * 128);
            acc0[t] = __builtin_amdgcn_mfma_f32_16x16x32_bf16(fa0, b, acc0[t], 0, 0, 0);
            acc1[t] = __builtin_amdgcn_mfma_f32_16x16x32_bf16(fa1, b, acc1[t], 0, 0, 0);
        }
    }

    // epilogue: C/D layout col=t*16+mr, row=quad*4+rr; scale by dis[row]
    #pragma unroll
    for (int rr = 0; rr < 4; rr++) {
        int ra = base + quad * 4 + rr;
        if (ra < N) {
            float ds = dis[ra];
            #pragma unroll
            for (int t = 0; t < 8; t++)
                C[(size_t)ra * HID + t * 16 + mr] = f2bf(acc0[t][rr] * ds);
        }
        int rb = base + 16 + quad * 4 + rr;
        if (rb < N) {
            float ds = dis[rb];
            #pragma unroll
            for (int t = 0; t < 8; t++)
                C[(size_t)rb * HID + t * 16 + mr] = f2bf(acc1[t][rr] * ds);
        }
    }
}

// ------- agg1: ONE WAVE per node. lane = ni(4) x fl(16). --------------------
// out[node] = bf16( relu( dis[node] * (h1s[node] + sum h1s[s]) + b1 ) )
// 4 neighbor rows per gather instruction, 2 gathers + next cols in flight,
// uniform trip count (no max-of-4-nodes divergence), shfl_xor(16,32) reduce.
__global__ __launch_bounds__(256) void agg1_k(const ushort* __restrict__ h,
                                              const int* __restrict__ col,
                                              const unsigned* __restrict__ offs,
                                              const float* __restrict__ dis,
                                              const float* __restrict__ b1,
                                              ushort* __restrict__ out, int N) {
    int node = blockIdx.x * 4 + (threadIdx.x >> 6);
    if (node >= N) return;
    int lane = threadIdx.x & 63;
    int ni = lane >> 4;          // neighbor slot 0..3
    int fl = lane & 15;          // feature group (8 bf16 each)
    const ushort* hb = h + (size_t)fl * 8;
    float a[8] = {0.f, 0.f, 0.f, 0.f, 0.f, 0.f, 0.f, 0.f};
    if (ni == 0) {   // self row
        uint4 v = *(const uint4*)(hb + (size_t)node * HID);
        const ushort* u = (const ushort*)&v;
        #pragma unroll
        for (int j = 0; j < 8; j++) a[j] = bf2f(u[j]);
    }
    unsigned p0 = offs[node], p1 = offs[node + 1];
    int sA = (p0 + ni     < p1) ? col[p0 + ni]     : -1;
    int sB = (p0 + ni + 4 < p1) ? col[p0 + ni + 4] : -1;
    for (unsigned p = p0; p < p1; p += 8) {
        int sC = (p + 8 + ni  < p1) ? col[p + 8 + ni]  : -1;
        int sD = (p + 12 + ni < p1) ? col[p + 12 + ni] : -1;
        if (sA >= 0) {
            uint4 v = *(const uint4*)(hb + (size_t)sA * HID);
            const ushort* u = (const ushort*)&v;
            #pragma unroll
            for (int j = 0; j < 8; j++) a[j] += bf2f(u[j]);
        }
        if (sB >= 0) {
            uint4 v = *(const uint4*)(hb + (size_t)sB * HID);
            const ushort* u = (const ushort*)&v;
            #pragma unroll
            for (int j = 0; j < 8; j++) a[j] += bf2f(u[j]);
        }
        sA = sC; sB = sD;
    }
    // reduce across the 4 neighbor slots (lane bits 4,5)
    #pragma unroll
    for (int j = 0; j < 8; j++) {
        a[j] += __shfl_xor(a[j], 16);
        a[j] += __shfl_xor(a[j], 32);
    }
    if (ni == 0) {
        float dd = dis[node];
        float4 bb0 = *(const float4*)(b1 + fl * 8);
        float4 bb1 = *(const float4*)(b1 + fl * 8 + 4);
        const float bb[8] = {bb0.x, bb0.y, bb0.z, bb0.w, bb1.x, bb1.y, bb1.z, bb1.w};
        __align__(16) ushort o[8];
        #pragma unroll
        for (int j = 0; j < 8; j++) o[j] = f2bf(fmaxf(a[j] * dd + bb[j], 0.f));
        *(uint4*)(out + (size_t)node * HID + (size_t)fl * 8) = *(const uint4*)o;
    }
}

// ------- GEMM2 MFMA, barrier-free: h2s[N,48p] = (ag1 @ W2) * dis[row] -------
__global__ __launch_bounds__(256) void gemm2_mfma(const ushort* __restrict__ A,
                                                  const ushort* __restrict__ W2p,
                                                  const float* __restrict__ dis,
                                                  ushort* __restrict__ h2, int N) {
    const int tid  = threadIdx.x;
    const int wave = tid >> 6;
    const int lane = tid & 63;
    const int quad = lane >> 4;
    const int mr   = lane & 15;
    const int base = (blockIdx.x * 4 + wave) * 32;
    if (base >= N) return;
    const int r0 = base + mr;
    const int r1 = base + 16 + mr;
    const bool ok0 = r0 < N, ok1 = r1 < N;
    const ushort* ap0 = A + (size_t)(ok0 ? r0 : 0) * HID + quad * 8;
    const ushort* ap1 = A + (size_t)(ok1 ? r1 : 0) * HID + quad * 8;
    const ushort* bp = W2p + quad * 384 + mr * 8;   // + ks*1536 + t*128

    f32x4v acc0[3], acc1[3];
    #pragma unroll
    for (int t = 0; t < 3; t++) {
        acc0[t] = (f32x4v){0.f, 0.f, 0.f, 0.f};
        acc1[t] = (f32x4v){0.f, 0.f, 0.f, 0.f};
    }
    #pragma unroll
    for (int ks = 0; ks < 4; ks++) {
        bf16x8 a0 = *(const bf16x8*)(ap0 + ks * 32);
        bf16x8 a1 = *(const bf16x8*)(ap1 + ks * 32);
        #pragma unroll
        for (int t = 0; t < 3; t++) {
            bf16x8 b = *(const bf16x8*)(bp + ks * 1536 + t * 128);
            acc0[t] = __builtin_amdgcn_mfma_f32_16x16x32_bf16(a0, b, acc0[t], 0, 0, 0);
            acc1[t] = __builtin_amdgcn_mfma_f32_16x16x32_bf16(a1, b, acc1[t], 0, 0, 0);
        }
    }
    #pragma unroll
    for (int rr = 0; rr < 4; rr++) {
        int ra = base + quad * 4 + rr;
        if (ra < N) {
            float ds = dis[ra];
            #pragma unroll
            for (int t = 0; t < 3; t++) {
                int c = t * 16 + mr;
                if (c < NC) h2[(size_t)ra * NCP + c] = f2bf(acc0[t][rr] * ds);
            }
        }
        int rb = base + 16 + quad * 4 + rr;
        if (rb < N) {
            float ds = dis[rb];
            #pragma unroll
            for (int t = 0; t < 3; t++) {
                int c = t * 16 + mr;
                if (c < NC) h2[(size_t)rb * NCP + c] = f2bf(acc1[t][rr] * ds);
            }
        }
    }
}

// ------- agg2 + b2 + log_softmax: ONE WAVE per node. lane = ni(8) x fl(8). --
// logits = dis[node] * (h2s[node] + sum h2s[s]) + b2; h2 rows padded to 48.
__global__ __launch_bounds__(256) void agg2_ls(const ushort* __restrict__ h2,
                                               const int* __restrict__ col,
                                               const unsigned* __restrict__ offs,
                                               const float* __restrict__ dis,
                                               const float* __restrict__ b2,
                                               float* __restrict__ out, int N) {
    int node = blockIdx.x * 4 + (threadIdx.x >> 6);
    if (node >= N) return;
    int lane = threadIdx.x & 63;
    int ni = lane >> 3;          // neighbor slot 0..7
    int fl = lane & 7;           // feature group
    const bool act = fl < 5;     // 5 x 8 = 40 classes
    const ushort* hb = h2 + (size_t)fl * 8;
    float a[8] = {0.f, 0.f, 0.f, 0.f, 0.f, 0.f, 0.f, 0.f};
    if (ni == 0 && act) {   // self row
        uint4 v = *(const uint4*)(hb + (size_t)node * NCP);
        const ushort* u = (const ushort*)&v;
        #pragma unroll
        for (int j = 0; j < 8; j++) a[j] = bf2f(u[j]);
    }
    unsigned p0 = offs[node], p1 = offs[node + 1];
    int sA = (p0 + ni     < p1) ? col[p0 + ni]     : -1;
    int sB = (p0 + ni + 8 < p1) ? col[p0 + ni + 8] : -1;
    for (unsigned p = p0; p < p1; p += 16) {
        int sC = (p + 16 + ni < p1) ? col[p + 16 + ni] : -1;
        int sD = (p + 24 + ni < p1) ? col[p + 24 + ni] : -1;
        if (sA >= 0 && act) {
            uint4 v = *(const uint4*)(hb + (size_t)sA * NCP);
            const ushort* u = (const ushort*)&v;
            #pragma unroll
            for (int j = 0; j < 8; j++) a[j] += bf2f(u[j]);
        }
        if (sB >= 0 && act) {
            uint4 v = *(const uint4*)(hb + (size_t)sB * NCP);
            const ushort* u = (const ushort*)&v;
            #pragma unroll
            for (int j = 0; j < 8; j++) a[j] += bf2f(u[j]);
        }
        sA = sC; sB = sD;
    }
    // reduce across the 8 neighbor slots (lane bits 3,4,5)
    #pragma unroll
    for (int j = 0; j < 8; j++) {
        a[j] += __shfl_xor(a[j], 8);
        a[j] += __shfl_xor(a[j], 16);
        a[j] += __shfl_xor(a[j], 32);
    }
    float dd = dis[node];
    float l[8];
    float m = -1e30f;
    if (act) {
        #pragma unroll
        for (int j = 0; j < 8; j++) {
            l[j] = a[j] * dd + b2[fl * 8 + j];
            m = fmaxf(m, l[j]);
        }
    }
    #pragma unroll
    for (int d = 1; d < 8; d <<= 1) m = fmaxf(m, __shfl_xor(m, d, 8));
    float s = 0.f;
    if (act) {
        #pragma unroll
        for (int j = 0; j < 8; j++) s += __expf(l[j] - m);
    }
    #pragma unroll
    for (int d = 1; d < 8; d <<= 1) s += __shfl_xor(s, d, 8);
    float lse = m + __logf(s);
    if (ni == 0 && act) {
        float* op = out + (size_t)node * NC + fl * 8;
        *(float4*)op       = make_float4(l[0]-lse, l[1]-lse, l[2]-lse, l[3]-lse);
        *(float4*)(op + 4) = make_float4(l[4]-lse, l[5]-lse, l[6]-lse, l[7]-lse);
    }
}

extern "C" void kernel_launch(void* const* d_in, const int* in_sizes, int n_in,
                              void* d_out, int out_size, void* d_ws, size_t ws_size,
                              hipStream_t stream) {
    const float* x  = (const float*)d_in[0];
    const int*   ei = (const int*)d_in[1];
    const float* W1 = (const float*)d_in[2];
    const float* b1 = (const float*)d_in[3];
    const float* W2 = (const float*)d_in[4];
    const float* b2 = (const float*)d_in[5];
    float* out = (float*)d_out;

    const int N = in_sizes[0] / F_IN;     // 100000
    const int E = in_sizes[1] / 2;        // 1600000
    const int* src = ei;
    const int* dst = ei + E;

    // ---- workspace layout ----
    char* ws = (char*)d_ws;
    size_t o = 0;
    unsigned* cnt  = (unsigned*)(ws + o); o += (size_t)N * 4;
    unsigned* cur  = (unsigned*)(ws + o); o += (size_t)N * 4;   // contiguous w/ cnt
    float*    dis  = (float*)   (ws + o); o += (size_t)N * 4;
    unsigned* offs = (unsigned*)(ws + o); o += (size_t)(N + 4) * 4;
    unsigned* bsums= (unsigned*)(ws + o); o += 4096;
    int*      col  = (int*)     (ws + o); o += (size_t)E * 4;
    o = (o + 15) & ~(size_t)15;
    ushort*   W1p  = (ushort*)  (ws + o); o += (size_t)F_IN * HID * 2;   // 128 KB
    o = (o + 15) & ~(size_t)15;
    ushort*   W2p  = (ushort*)  (ws + o); o += 6144 * 2;                 // 12 KB
    o = (o + 15) & ~(size_t)15;
    ushort*   h1   = (ushort*)  (ws + o); o += (size_t)N * HID * 2;      // 25.6 MB
    o = (o + 15) & ~(size_t)15;
    ushort*   ag1  = (ushort*)  (ws + o); o += (size_t)N * HID * 2;      // 25.6 MB
    o = (o + 15) & ~(size_t)15;
    ushort*   h2   = (ushort*)  (ws + o); o += (size_t)N * NCP * 2;      // 9.6 MB

    const int nb = (N + 1023) / 1024;
    const int EB = (E + 255) / 256;
    const int PB = (65536 + 6144 + 255) / 256;   // 280 pack blocks
    const int GB = (N + 127) / 128;              // gemm1 blocks (first)

    // degree + weight pack in one launch (cnt and cur zeroed in one memset)
    hipMemsetAsync(cnt, 0, (size_t)N * 8, stream);
    prep_k<<<EB + PB, 256, 0, stream>>>(dst, E, EB, cnt, W1, W2, W1p, W2p);
    scan_block<<<nb, 1024, 0, stream>>>(cnt, offs, bsums, dis, N);
    scan_add2<<<nb, 1024, 0, stream>>>(offs, bsums, N, (unsigned)E);

    // CSR fill + layer-1 GEMM: independent -> ONE dispatch, concurrent
    fill_gemm1<<<GB + EB, 256, 0, stream>>>(src, dst, offs, cur, col, E, GB,
                                            x, W1p, dis, h1, N);

    agg1_k<<<(N + 3) / 4, 256, 0, stream>>>(h1, col, offs, dis, b1, ag1, N);

    // layer 2
    gemm2_mfma<<<(N + 127) / 128, 256, 0, stream>>>(ag1, W2p, dis, h2, N);
    agg2_ls<<<(N + 3) / 4, 256, 0, stream>>>(h2, col, offs, dis, b2, out, N);
}

// Round 4
// 586.164 us; speedup vs baseline: 1.0215x; 1.0215x over previous
//
#include <hip/hip_runtime.h>
#include <hip/hip_bf16.h>

// GCN 2-layer forward. CSR pull-aggregation, wave-per-node gathers.
// GEMMs are BARRIER-FREE and LDS-FREE. This round (R3 resubmit — infra flake):
// (1) RANK TRICK: count-phase atomicAdd return value saved as per-edge rank;
//     fill_csr becomes atomic-free (col[offs[d]+rank[e]] = src[e]).
// (2) gemm1 restructured: 16 rows/wave (was 32), grid 781->1563 blocks
//     (3->6 blocks/CU), A-prefetch distance 4 (was 2), K-loop fully unrolled
//     so the prefetch ring stays in registers. Attacks the measured 28%
//     occupancy / latency-bound profile of the merged fill+gemm1 dispatch.
// N=100000, F_IN=512, HID=128, C=40, E=1.6M

#define F_IN 512
#define HID  128
#define NC   40
#define NCP  48   // padded h2 row: 96 B = exactly two 64 B lines, 16 B aligned

typedef __attribute__((ext_vector_type(8))) short bf16x8;
typedef __attribute__((ext_vector_type(4))) float f32x4v;

__device__ __forceinline__ ushort f2bf(float f) {
    unsigned r;
    asm("v_cvt_pk_bf16_f32 %0, %1, %1" : "=v"(r) : "v"(f));   // RNE, 1 instr
    return (ushort)r;
}
__device__ __forceinline__ unsigned cvtpk(float a, float b) {
    unsigned r;
    asm("v_cvt_pk_bf16_f32 %0, %1, %2" : "=v"(r) : "v"(a), "v"(b));
    return r;
}
__device__ __forceinline__ float bf2f(ushort u) {
    return __uint_as_float((unsigned)u << 16);
}
__device__ __forceinline__ bf16x8 cvt8(float4 lo, float4 hi) {
    union { unsigned u[4]; bf16x8 v; } t;
    t.u[0] = cvtpk(lo.x, lo.y); t.u[1] = cvtpk(lo.z, lo.w);
    t.u[2] = cvtpk(hi.x, hi.y); t.u[3] = cvtpk(hi.z, hi.w);
    return t.v;
}

// ---------------- degree count + rank (real edges) + weight pack ------------
// Blocks [0, EB): per-edge atomic degree count; returned old value = rank of
// this edge within its dst segment (order irrelevant for sum-aggregation).
// Blocks [EB, EB+280): pack W1 -> W1p bf16 and W2 -> W2p bf16 (padded).
// W1p: [s(16)][kb(4)][n(128)][j(8)], k = s*32+kb*8+j   (65536 elems)
// W2p: [ks(4)][kb(4)][n(48)][j(8)],  k = ks*32+kb*8+j  (6144 elems, n>=40 -> 0)
__global__ void prep_k(const int* __restrict__ dst, int E, int EB,
                       unsigned* __restrict__ cnt, int* __restrict__ rank,
                       const float* __restrict__ W1, const float* __restrict__ W2,
                       ushort* __restrict__ W1p, ushort* __restrict__ W2p) {
    int b = blockIdx.x;
    if (b < EB) {
        int t = b * 256 + threadIdx.x;
        if (t < E) rank[t] = (int)atomicAdd(&cnt[dst[t]], 1u);
        return;
    }
    int t = (b - EB) * 256 + threadIdx.x;
    if (t < 65536) {
        int j = t & 7, n = (t >> 3) & 127, kb = (t >> 10) & 3, s = t >> 12;
        int k = s * 32 + kb * 8 + j;
        W1p[t] = f2bf(W1[(size_t)k * HID + n]);
    } else {
        int q = t - 65536;
        if (q < 6144) {
            int j = q & 7;
            int i2 = q >> 3;
            int n = i2 % 48;
            int i3 = i2 / 48;
            int kb = i3 & 3, ks = i3 >> 2;
            int k = ks * 32 + kb * 8 + j;
            float v = (n < NC) ? W2[(size_t)k * NC + n] : 0.f;
            W2p[q] = f2bf(v);
        }
    }
}

// ---------------- block-local exclusive scan (shfl-based) + fused dis -------
__global__ __launch_bounds__(1024) void scan_block(const unsigned* __restrict__ cnt,
                                                   unsigned* __restrict__ offs,
                                                   unsigned* __restrict__ bsums,
                                                   float* __restrict__ dis, int N) {
    int tid = threadIdx.x;
    int i = blockIdx.x * 1024 + tid;
    unsigned v = (i < N) ? cnt[i] : 0u;
    if (i < N) dis[i] = rsqrtf((float)v + 1.0f);   // +1 = self loop
    int lane = tid & 63, w = tid >> 6;
    unsigned s = v;
    #pragma unroll
    for (int d = 1; d < 64; d <<= 1) {
        unsigned t = __shfl_up(s, d, 64);
        if (lane >= d) s += t;
    }
    __shared__ unsigned wt[16];
    if (lane == 63) wt[w] = s;
    __syncthreads();
    unsigned add = 0;
    #pragma unroll
    for (int j = 0; j < 16; j++) add += (j < w) ? wt[j] : 0u;
    unsigned incl = s + add;
    if (i < N) offs[i] = incl - v;                 // exclusive within block
    if (tid == 1023) bsums[blockIdx.x] = incl;     // raw block total
}

// ---------------- add bsums prefix (computed in-block, no serial kernel) ----
__global__ __launch_bounds__(1024) void scan_add2(unsigned* __restrict__ offs,
                                                  const unsigned* __restrict__ bsums,
                                                  int N, unsigned total) {
    int i = blockIdx.x * 1024 + threadIdx.x;
    int lane = threadIdx.x & 63;
    unsigned s = 0;
    for (int j = lane; j < (int)blockIdx.x; j += 64) s += bsums[j];
    #pragma unroll
    for (int d = 1; d < 64; d <<= 1) s += __shfl_xor(s, d, 64);
    if (i < N) offs[i] += s;
    if (i == 0) offs[N] = total;
}

// ------- MERGED: gemm1 (blocks [0,GB)) + fill_csr (blocks [GB,GB+EB)) -------
// fill is now ATOMIC-FREE (rank precomputed in prep_k).
// gemm1: h1s[N,128] = (bf16(x) @ W1) * dis[row]; 16 rows/wave, 64 rows/block,
// A-prefetch ring of 4 steps (8 float4 loads in flight), full K unroll.
__global__ __launch_bounds__(256) void fill_gemm1(
        const int* __restrict__ src, const int* __restrict__ dst,
        const unsigned* __restrict__ offs, const int* __restrict__ rank,
        int* __restrict__ col, int E, int GB,
        const float* __restrict__ A, const ushort* __restrict__ Bp,
        const float* __restrict__ dis, ushort* __restrict__ C, int N) {
    if (blockIdx.x >= GB) {
        // ---- fill_csr part (atomic-free) ----
        int t = (blockIdx.x - GB) * 256 + threadIdx.x;
        if (t < E) {
            int d = dst[t];
            col[offs[d] + (unsigned)rank[t]] = src[t];
        }
        return;
    }
    // ---- gemm1 part: 16 rows per wave ----
    const int tid  = threadIdx.x;
    const int wave = tid >> 6;
    const int lane = tid & 63;
    const int quad = lane >> 4;
    const int mr   = lane & 15;
    const int base = (blockIdx.x * 4 + wave) * 16;
    if (base >= N) return;
    const int r0 = base + mr;
    const bool ok0 = r0 < N;
    const float* ap0 = A + (size_t)(ok0 ? r0 : 0) * F_IN + quad * 8;
    const ushort* bp = Bp + quad * 1024 + mr * 8;   // + s*4096 + t*128

    f32x4v acc0[8];
    #pragma unroll
    for (int t = 0; t < 8; t++) acc0[t] = (f32x4v){0.f, 0.f, 0.f, 0.f};

    // A prefetch ring, distance 4: av[s&3] = {lo, hi} for step s
    float4 av[4][2];
    #pragma unroll
    for (int b = 0; b < 4; b++) {
        av[b][0] = *(const float4*)(ap0 + b * 32);
        av[b][1] = *(const float4*)(ap0 + b * 32 + 4);
    }

    #pragma unroll
    for (int s = 0; s < 16; s++) {
        bf16x8 fa0 = cvt8(av[s & 3][0], av[s & 3][1]);
        if (s < 12) {   // reload this ring slot with step s+4 (distance 4)
            av[s & 3][0] = *(const float4*)(ap0 + (s + 4) * 32);
            av[s & 3][1] = *(const float4*)(ap0 + (s + 4) * 32 + 4);
        }
        const ushort* bs = bp + s * 4096;
        #pragma unroll
        for (int t = 0; t < 8; t++) {
            bf16x8 b = *(const bf16x8*)(bs + t * 128);
            acc0[t] = __builtin_amdgcn_mfma_f32_16x16x32_bf16(fa0, b, acc0[t], 0, 0, 0);
        }
    }

    // epilogue: C/D layout col=t*16+mr, row=quad*4+rr; scale by dis[row]
    #pragma unroll
    for (int rr = 0; rr < 4; rr++) {
        int ra = base + quad * 4 + rr;
        if (ra < N) {
            float ds = dis[ra];
            #pragma unroll
            for (int t = 0; t < 8; t++)
                C[(size_t)ra * HID + t * 16 + mr] = f2bf(acc0[t][rr] * ds);
        }
    }
}

// ------- agg1: ONE WAVE per node. lane = ni(4) x fl(16). --------------------
// out[node] = bf16( relu( dis[node] * (h1s[node] + sum h1s[s]) + b1 ) )
__global__ __launch_bounds__(256) void agg1_k(const ushort* __restrict__ h,
                                              const int* __restrict__ col,
                                              const unsigned* __restrict__ offs,
                                              const float* __restrict__ dis,
                                              const float* __restrict__ b1,
                                              ushort* __restrict__ out, int N) {
    int node = blockIdx.x * 4 + (threadIdx.x >> 6);
    if (node >= N) return;
    int lane = threadIdx.x & 63;
    int ni = lane >> 4;          // neighbor slot 0..3
    int fl = lane & 15;          // feature group (8 bf16 each)
    const ushort* hb = h + (size_t)fl * 8;
    float a[8] = {0.f, 0.f, 0.f, 0.f, 0.f, 0.f, 0.f, 0.f};
    if (ni == 0) {   // self row
        uint4 v = *(const uint4*)(hb + (size_t)node * HID);
        const ushort* u = (const ushort*)&v;
        #pragma unroll
        for (int j = 0; j < 8; j++) a[j] = bf2f(u[j]);
    }
    unsigned p0 = offs[node], p1 = offs[node + 1];
    int sA = (p0 + ni     < p1) ? col[p0 + ni]     : -1;
    int sB = (p0 + ni + 4 < p1) ? col[p0 + ni + 4] : -1;
    for (unsigned p = p0; p < p1; p += 8) {
        int sC = (p + 8 + ni  < p1) ? col[p + 8 + ni]  : -1;
        int sD = (p + 12 + ni < p1) ? col[p + 12 + ni] : -1;
        if (sA >= 0) {
            uint4 v = *(const uint4*)(hb + (size_t)sA * HID);
            const ushort* u = (const ushort*)&v;
            #pragma unroll
            for (int j = 0; j < 8; j++) a[j] += bf2f(u[j]);
        }
        if (sB >= 0) {
            uint4 v = *(const uint4*)(hb + (size_t)sB * HID);
            const ushort* u = (const ushort*)&v;
            #pragma unroll
            for (int j = 0; j < 8; j++) a[j] += bf2f(u[j]);
        }
        sA = sC; sB = sD;
    }
    // reduce across the 4 neighbor slots (lane bits 4,5)
    #pragma unroll
    for (int j = 0; j < 8; j++) {
        a[j] += __shfl_xor(a[j], 16);
        a[j] += __shfl_xor(a[j], 32);
    }
    if (ni == 0) {
        float dd = dis[node];
        float4 bb0 = *(const float4*)(b1 + fl * 8);
        float4 bb1 = *(const float4*)(b1 + fl * 8 + 4);
        const float bb[8] = {bb0.x, bb0.y, bb0.z, bb0.w, bb1.x, bb1.y, bb1.z, bb1.w};
        __align__(16) ushort o[8];
        #pragma unroll
        for (int j = 0; j < 8; j++) o[j] = f2bf(fmaxf(a[j] * dd + bb[j], 0.f));
        *(uint4*)(out + (size_t)node * HID + (size_t)fl * 8) = *(const uint4*)o;
    }
}

// ------- GEMM2 MFMA, barrier-free: h2s[N,48p] = (ag1 @ W2) * dis[row] -------
__global__ __launch_bounds__(256) void gemm2_mfma(const ushort* __restrict__ A,
                                                  const ushort* __restrict__ W2p,
                                                  const float* __restrict__ dis,
                                                  ushort* __restrict__ h2, int N) {
    const int tid  = threadIdx.x;
    const int wave = tid >> 6;
    const int lane = tid & 63;
    const int quad = lane >> 4;
    const int mr   = lane & 15;
    const int base = (blockIdx.x * 4 + wave) * 32;
    if (base >= N) return;
    const int r0 = base + mr;
    const int r1 = base + 16 + mr;
    const bool ok0 = r0 < N, ok1 = r1 < N;
    const ushort* ap0 = A + (size_t)(ok0 ? r0 : 0) * HID + quad * 8;
    const ushort* ap1 = A + (size_t)(ok1 ? r1 : 0) * HID + quad * 8;
    const ushort* bp = W2p + quad * 384 + mr * 8;   // + ks*1536 + t*128

    f32x4v acc0[3], acc1[3];
    #pragma unroll
    for (int t = 0; t < 3; t++) {
        acc0[t] = (f32x4v){0.f, 0.f, 0.f, 0.f};
        acc1[t] = (f32x4v){0.f, 0.f, 0.f, 0.f};
    }
    #pragma unroll
    for (int ks = 0; ks < 4; ks++) {
        bf16x8 a0 = *(const bf16x8*)(ap0 + ks * 32);
        bf16x8 a1 = *(const bf16x8*)(ap1 + ks * 32);
        #pragma unroll
        for (int t = 0; t < 3; t++) {
            bf16x8 b = *(const bf16x8*)(bp + ks * 1536 + t * 128);
            acc0[t] = __builtin_amdgcn_mfma_f32_16x16x32_bf16(a0, b, acc0[t], 0, 0, 0);
            acc1[t] = __builtin_amdgcn_mfma_f32_16x16x32_bf16(a1, b, acc1[t], 0, 0, 0);
        }
    }
    #pragma unroll
    for (int rr = 0; rr < 4; rr++) {
        int ra = base + quad * 4 + rr;
        if (ra < N) {
            float ds = dis[ra];
            #pragma unroll
            for (int t = 0; t < 3; t++) {
                int c = t * 16 + mr;
                if (c < NC) h2[(size_t)ra * NCP + c] = f2bf(acc0[t][rr] * ds);
            }
        }
        int rb = base + 16 + quad * 4 + rr;
        if (rb < N) {
            float ds = dis[rb];
            #pragma unroll
            for (int t = 0; t < 3; t++) {
                int c = t * 16 + mr;
                if (c < NC) h2[(size_t)rb * NCP + c] = f2bf(acc1[t][rr] * ds);
            }
        }
    }
}

// ------- agg2 + b2 + log_softmax: ONE WAVE per node. lane = ni(8) x fl(8). --
// logits = dis[node] * (h2s[node] + sum h2s[s]) + b2; h2 rows padded to 48.
__global__ __launch_bounds__(256) void agg2_ls(const ushort* __restrict__ h2,
                                               const int* __restrict__ col,
                                               const unsigned* __restrict__ offs,
                                               const float* __restrict__ dis,
                                               const float* __restrict__ b2,
                                               float* __restrict__ out, int N) {
    int node = blockIdx.x * 4 + (threadIdx.x >> 6);
    if (node >= N) return;
    int lane = threadIdx.x & 63;
    int ni = lane >> 3;          // neighbor slot 0..7
    int fl = lane & 7;           // feature group
    const bool act = fl < 5;     // 5 x 8 = 40 classes
    const ushort* hb = h2 + (size_t)fl * 8;
    float a[8] = {0.f, 0.f, 0.f, 0.f, 0.f, 0.f, 0.f, 0.f};
    if (ni == 0 && act) {   // self row
        uint4 v = *(const uint4*)(hb + (size_t)node * NCP);
        const ushort* u = (const ushort*)&v;
        #pragma unroll
        for (int j = 0; j < 8; j++) a[j] = bf2f(u[j]);
    }
    unsigned p0 = offs[node], p1 = offs[node + 1];
    int sA = (p0 + ni     < p1) ? col[p0 + ni]     : -1;
    int sB = (p0 + ni + 8 < p1) ? col[p0 + ni + 8] : -1;
    for (unsigned p = p0; p < p1; p += 16) {
        int sC = (p + 16 + ni < p1) ? col[p + 16 + ni] : -1;
        int sD = (p + 24 + ni < p1) ? col[p + 24 + ni] : -1;
        if (sA >= 0 && act) {
            uint4 v = *(const uint4*)(hb + (size_t)sA * NCP);
            const ushort* u = (const ushort*)&v;
            #pragma unroll
            for (int j = 0; j < 8; j++) a[j] += bf2f(u[j]);
        }
        if (sB >= 0 && act) {
            uint4 v = *(const uint4*)(hb + (size_t)sB * NCP);
            const ushort* u = (const ushort*)&v;
            #pragma unroll
            for (int j = 0; j < 8; j++) a[j] += bf2f(u[j]);
        }
        sA = sC; sB = sD;
    }
    // reduce across the 8 neighbor slots (lane bits 3,4,5)
    #pragma unroll
    for (int j = 0; j < 8; j++) {
        a[j] += __shfl_xor(a[j], 8);
        a[j] += __shfl_xor(a[j], 16);
        a[j] += __shfl_xor(a[j], 32);
    }
    float dd = dis[node];
    float l[8];
    float m = -1e30f;
    if (act) {
        #pragma unroll
        for (int j = 0; j < 8; j++) {
            l[j] = a[j] * dd + b2[fl * 8 + j];
            m = fmaxf(m, l[j]);
        }
    }
    #pragma unroll
    for (int d = 1; d < 8; d <<= 1) m = fmaxf(m, __shfl_xor(m, d, 8));
    float s = 0.f;
    if (act) {
        #pragma unroll
        for (int j = 0; j < 8; j++) s += __expf(l[j] - m);
    }
    #pragma unroll
    for (int d = 1; d < 8; d <<= 1) s += __shfl_xor(s, d, 8);
    float lse = m + __logf(s);
    if (ni == 0 && act) {
        float* op = out + (size_t)node * NC + fl * 8;
        *(float4*)op       = make_float4(l[0]-lse, l[1]-lse, l[2]-lse, l[3]-lse);
        *(float4*)(op + 4) = make_float4(l[4]-lse, l[5]-lse, l[6]-lse, l[7]-lse);
    }
}

extern "C" void kernel_launch(void* const* d_in, const int* in_sizes, int n_in,
                              void* d_out, int out_size, void* d_ws, size_t ws_size,
                              hipStream_t stream) {
    const float* x  = (const float*)d_in[0];
    const int*   ei = (const int*)d_in[1];
    const float* W1 = (const float*)d_in[2];
    const float* b1 = (const float*)d_in[3];
    const float* W2 = (const float*)d_in[4];
    const float* b2 = (const float*)d_in[5];
    float* out = (float*)d_out;

    const int N = in_sizes[0] / F_IN;     // 100000
    const int E = in_sizes[1] / 2;        // 1600000
    const int* src = ei;
    const int* dst = ei + E;

    // ---- workspace layout ----
    char* ws = (char*)d_ws;
    size_t o = 0;
    unsigned* cnt  = (unsigned*)(ws + o); o += (size_t)N * 4;
    float*    dis  = (float*)   (ws + o); o += (size_t)N * 4;
    unsigned* offs = (unsigned*)(ws + o); o += (size_t)(N + 4) * 4;
    unsigned* bsums= (unsigned*)(ws + o); o += 4096;
    int*      rank = (int*)     (ws + o); o += (size_t)E * 4;            // 6.4 MB
    int*      col  = (int*)     (ws + o); o += (size_t)E * 4;            // 6.4 MB
    o = (o + 15) & ~(size_t)15;
    ushort*   W1p  = (ushort*)  (ws + o); o += (size_t)F_IN * HID * 2;   // 128 KB
    o = (o + 15) & ~(size_t)15;
    ushort*   W2p  = (ushort*)  (ws + o); o += 6144 * 2;                 // 12 KB
    o = (o + 15) & ~(size_t)15;
    ushort*   h1   = (ushort*)  (ws + o); o += (size_t)N * HID * 2;      // 25.6 MB
    o = (o + 15) & ~(size_t)15;
    ushort*   ag1  = (ushort*)  (ws + o); o += (size_t)N * HID * 2;      // 25.6 MB
    o = (o + 15) & ~(size_t)15;
    ushort*   h2   = (ushort*)  (ws + o); o += (size_t)N * NCP * 2;      // 9.6 MB

    const int nb = (N + 1023) / 1024;
    const int EB = (E + 255) / 256;
    const int PB = (65536 + 6144 + 255) / 256;   // 280 pack blocks
    const int GB = (N + 63) / 64;                // gemm1 blocks (16 rows/wave)

    // degree count (with rank capture) + weight pack in one launch
    hipMemsetAsync(cnt, 0, (size_t)N * 4, stream);
    prep_k<<<EB + PB, 256, 0, stream>>>(dst, E, EB, cnt, rank, W1, W2, W1p, W2p);
    scan_block<<<nb, 1024, 0, stream>>>(cnt, offs, bsums, dis, N);
    scan_add2<<<nb, 1024, 0, stream>>>(offs, bsums, N, (unsigned)E);

    // CSR fill (atomic-free) + layer-1 GEMM: ONE dispatch, concurrent
    fill_gemm1<<<GB + EB, 256, 0, stream>>>(src, dst, offs, rank, col, E, GB,
                                            x, W1p, dis, h1, N);

    agg1_k<<<(N + 3) / 4, 256, 0, stream>>>(h1, col, offs, dis, b1, ag1, N);

    // layer 2
    gemm2_mfma<<<(N + 127) / 128, 256, 0, stream>>>(ag1, W2p, dis, h2, N);
    agg2_ls<<<(N + 3) / 4, 256, 0, stream>>>(h2, col, offs, dis, b2, out, N);
}